// Round 1
// baseline (1175.710 us; speedup 1.0000x reference)
//
#include <hip/hip_runtime.h>

typedef unsigned short ushort_t;
typedef __attribute__((ext_vector_type(8))) short short8;
typedef __attribute__((ext_vector_type(4))) float f32x4;

#define MTOT 28672   // B*S = 8*3584
#define H_   1024

static __device__ __forceinline__ float b2f(ushort_t u) {
    return __uint_as_float(((unsigned)u) << 16);
}
static __device__ __forceinline__ ushort_t f2b(float f) {
    unsigned u = __float_as_uint(f);
    u += 0x7fffu + ((u >> 16) & 1u);
    return (ushort_t)(u >> 16);
}
static __device__ __forceinline__ float ld_res(const float* p, long i) { return p[i]; }
static __device__ __forceinline__ float ld_res(const ushort_t* p, long i) { return b2f(p[i]); }

// ---------------- fp32 -> bf16 conversion (n % 1024 == 0), 4 elems/thread ----------------
__global__ __launch_bounds__(256)
void f2b_kernel(const float* __restrict__ in, ushort_t* __restrict__ out)
{
    size_t i = (size_t)blockIdx.x * 256 + threadIdx.x;
    float4 v = ((const float4*)in)[i];
    ushort4 o;
    o.x = f2b(v.x); o.y = f2b(v.y); o.z = f2b(v.z); o.w = f2b(v.w);
    ((ushort4*)out)[i] = o;
}

// ---------------- bf16 GEMM, C = A @ Bt^T (+bias, +relu / +residual), bf16 out ----------------
// A [M,K] bf16 row-major, Bt [N,K] bf16 row-major (K contiguous). M%128==0, N%128==0, K%32==0.
// EPI: 0 = bias, 1 = bias+relu, 2 = bias+residual(Res [M,N], ResT fp32 or bf16)
template<int EPI, typename ResT>
__global__ __launch_bounds__(256, 2)
void gemm_bt(const ushort_t* __restrict__ A, const ushort_t* __restrict__ Bt,
             const float* __restrict__ bias, const ResT* __restrict__ Res,
             ushort_t* __restrict__ C, int N, int K)
{
    __shared__ __align__(16) ushort_t Atile[128 * 32];
    __shared__ __align__(16) ushort_t Btile[128 * 32];
    const int tid  = threadIdx.x;
    const int wave = tid >> 6;
    const int lane = tid & 63;
    const int wr = wave >> 1, wc = wave & 1;   // 2x2 waves, 64x64 each
    const long row0 = (long)blockIdx.y * 128;
    const long col0 = (long)blockIdx.x * 128;
    const int kg = lane >> 4;   // 0..3 -> k-group of 8
    const int fr = lane & 15;

    f32x4 acc[4][4] = {};

    // staging: tile = 128 rows x 32 cols bf16 = 8192 B = 512 x 16B chunks; 256 threads -> 2 rounds
    const int c0 = tid, c1 = tid + 256;
    const ushort_t* gA0 = A  + (row0 + (c0 >> 2)) * (long)K + (c0 & 3) * 8;
    const ushort_t* gA1 = A  + (row0 + (c1 >> 2)) * (long)K + (c1 & 3) * 8;
    const ushort_t* gB0 = Bt + (col0 + (c0 >> 2)) * (long)K + (c0 & 3) * 8;
    const ushort_t* gB1 = Bt + (col0 + (c1 >> 2)) * (long)K + (c1 & 3) * 8;
    ushort_t* lA0 = &Atile[(wave * 64) * 8];          // wave-uniform LDS bases; lane lands at +lane*16B
    ushort_t* lA1 = &Atile[(256 + wave * 64) * 8];
    ushort_t* lB0 = &Btile[(wave * 64) * 8];
    ushort_t* lB1 = &Btile[(256 + wave * 64) * 8];

    for (int k0 = 0; k0 < K; k0 += 32) {
        __builtin_amdgcn_global_load_lds((const __attribute__((address_space(1))) void*)(gA0 + k0),
                                         (__attribute__((address_space(3))) void*)lA0, 16, 0, 0);
        __builtin_amdgcn_global_load_lds((const __attribute__((address_space(1))) void*)(gA1 + k0),
                                         (__attribute__((address_space(3))) void*)lA1, 16, 0, 0);
        __builtin_amdgcn_global_load_lds((const __attribute__((address_space(1))) void*)(gB0 + k0),
                                         (__attribute__((address_space(3))) void*)lB0, 16, 0, 0);
        __builtin_amdgcn_global_load_lds((const __attribute__((address_space(1))) void*)(gB1 + k0),
                                         (__attribute__((address_space(3))) void*)lB1, 16, 0, 0);
        __syncthreads();

        short8 af[4], bfr[4];
        #pragma unroll
        for (int m = 0; m < 4; ++m)
            af[m] = *(const short8*)&Atile[(wr * 64 + m * 16 + fr) * 32 + kg * 8];
        #pragma unroll
        for (int n = 0; n < 4; ++n)
            bfr[n] = *(const short8*)&Btile[(wc * 64 + n * 16 + fr) * 32 + kg * 8];
        #pragma unroll
        for (int m = 0; m < 4; ++m)
            #pragma unroll
            for (int n = 0; n < 4; ++n)
                acc[m][n] = __builtin_amdgcn_mfma_f32_16x16x32_bf16(af[m], bfr[n], acc[m][n], 0, 0, 0);
        __syncthreads();
    }

    // epilogue: C/D layout col=lane&15, row=(lane>>4)*4+reg  [verified m89/m91]
    #pragma unroll
    for (int n = 0; n < 4; ++n) {
        long cg = col0 + wc * 64 + n * 16 + fr;
        float bv = bias[cg];
        #pragma unroll
        for (int m = 0; m < 4; ++m) {
            long rbase = row0 + wr * 64 + m * 16 + kg * 4;
            #pragma unroll
            for (int q = 0; q < 4; ++q) {
                float v = acc[m][n][q] + bv;
                if constexpr (EPI == 1) v = fmaxf(v, 0.f);
                if constexpr (EPI == 2) v += ld_res(Res, (rbase + q) * (long)N + cg);
                C[(rbase + q) * (long)N + cg] = f2b(v);
            }
        }
    }
}

// ---------------- per-(window,head) attention: q,k,v [7,64]; one wave per block ----------------
__global__ __launch_bounds__(64)
void attn_kernel(const ushort_t* __restrict__ qkv, ushort_t* __restrict__ o)
{
    const int bid  = blockIdx.x;
    const int win  = bid >> 4;
    const int head = bid & 15;
    const int lane = threadIdx.x;
    __shared__ float qs[7][64], ks[7][64], vs[7][64];
    __shared__ float sc[7][8], pr[7][8];
    const long t0 = (long)win * 7;
    const ushort_t* base = qkv + t0 * 3072 + head * 64 + lane;
    #pragma unroll
    for (int i = 0; i < 7; ++i) {
        qs[i][lane] = b2f(base[(long)i * 3072]);
        ks[i][lane] = b2f(base[(long)i * 3072 + 1024]);
        vs[i][lane] = b2f(base[(long)i * 3072 + 2048]);
    }
    __syncthreads();
    if (lane < 49) {
        int i = lane / 7, j = lane % 7;
        float a = 0.f;
        #pragma unroll
        for (int d = 0; d < 64; ++d) a += qs[i][d] * ks[j][d];
        sc[i][j] = a * 0.125f;   // 1/sqrt(64)
    }
    __syncthreads();
    if (lane < 7) {
        float m = sc[lane][0];
        #pragma unroll
        for (int j = 1; j < 7; ++j) m = fmaxf(m, sc[lane][j]);
        float e[7], den = 0.f;
        #pragma unroll
        for (int j = 0; j < 7; ++j) { e[j] = __expf(sc[lane][j] - m); den += e[j]; }
        float inv = 1.f / den;
        #pragma unroll
        for (int j = 0; j < 7; ++j) pr[lane][j] = e[j] * inv;
    }
    __syncthreads();
    ushort_t* ob = o + t0 * 1024 + head * 64 + lane;
    #pragma unroll
    for (int i = 0; i < 7; ++i) {
        float a = 0.f;
        #pragma unroll
        for (int j = 0; j < 7; ++j) a += pr[i][j] * vs[j][lane];
        ob[(long)i * 1024] = f2b(a);
    }
}

// ---------------- row LayerNorm over H=1024; 256 threads, 4 elems/thread ----------------
template<typename OutT>
__global__ __launch_bounds__(256)
void ln_kernel(const ushort_t* in, OutT* out,
               const float* __restrict__ g, const float* __restrict__ b)
{
    const long row = blockIdx.x;
    const int tid = threadIdx.x;
    const ushort_t* p = in + row * H_;
    ushort4 raw = ((const ushort4*)p)[tid];
    float x0 = b2f(raw.x), x1 = b2f(raw.y), x2 = b2f(raw.z), x3 = b2f(raw.w);
    float s  = x0 + x1 + x2 + x3;
    float ss = x0*x0 + x1*x1 + x2*x2 + x3*x3;
    #pragma unroll
    for (int off = 32; off > 0; off >>= 1) {
        s  += __shfl_down(s,  off, 64);
        ss += __shfl_down(ss, off, 64);
    }
    __shared__ float rs[4], rss[4];
    const int wave = tid >> 6, lane = tid & 63;
    if (lane == 0) { rs[wave] = s; rss[wave] = ss; }
    __syncthreads();
    float S  = rs[0] + rs[1] + rs[2] + rs[3];
    float SS = rss[0] + rss[1] + rss[2] + rss[3];
    float mean = S * (1.f / 1024.f);
    float var  = SS * (1.f / 1024.f) - mean * mean;
    float inv  = rsqrtf(var + 1e-5f);
    float4 gv = ((const float4*)g)[tid];
    float4 bv = ((const float4*)b)[tid];
    float y0 = (x0 - mean) * inv * gv.x + bv.x;
    float y1 = (x1 - mean) * inv * gv.y + bv.y;
    float y2 = (x2 - mean) * inv * gv.z + bv.z;
    float y3 = (x3 - mean) * inv * gv.w + bv.w;
    if constexpr (sizeof(OutT) == 2) {
        ushort4 ov; ov.x = f2b(y0); ov.y = f2b(y1); ov.z = f2b(y2); ov.w = f2b(y3);
        ((ushort4*)out)[row * 256 + tid] = ov;
    } else {
        float4 ov; ov.x = y0; ov.y = y1; ov.z = y2; ov.w = y3;
        ((float4*)out)[row * 256 + tid] = ov;
    }
}

// ---------------- launch ----------------
extern "C" void kernel_launch(void* const* d_in, const int* in_sizes, int n_in,
                              void* d_out, int out_size, void* d_ws, size_t ws_size,
                              hipStream_t stream)
{
    const float* x      = (const float*)d_in[0];
    const float* wqkv_f = (const float*)d_in[1];
    const float* bqkv   = (const float*)d_in[2];
    const float* wout_f = (const float*)d_in[3];
    const float* bout   = (const float*)d_in[4];
    const float* ln1g   = (const float*)d_in[5];
    const float* ln1b   = (const float*)d_in[6];
    const float* ln2g   = (const float*)d_in[7];
    const float* ln2b   = (const float*)d_in[8];
    const float* wff1_f = (const float*)d_in[9];
    const float* bff1   = (const float*)d_in[10];
    const float* wff2_f = (const float*)d_in[11];
    const float* bff2   = (const float*)d_in[12];
    float* out = (float*)d_out;

    const size_t WQKV_N = 3072l * 1024, WOUT_N = 1024l * 1024;
    const size_t WFF1_N = 4096l * 1024, WFF2_N = 1024l * 4096;
    const size_t welems = WQKV_N + WOUT_N + WFF1_N + WFF2_N;

    // chunk rows R: multiple of lcm(7,128)=896; per-chunk arena = R*14336 B + weights
    int nc = 1;
    while (nc < 32 && (size_t)(MTOT / nc) * 14336 + welems * 2 > ws_size) nc <<= 1;
    const long R = MTOT / nc;

    char* ws = (char*)d_ws;
    ushort_t* qkv  = (ushort_t*)ws;                          // [R,3072]
    ushort_t* obuf = (ushort_t*)(ws + (size_t)R * 3072 * 2); // [R,1024]
    ushort_t* ff   = qkv;                                    // [R,4096] reuses qkv+obuf
    ushort_t* ybuf = (ushort_t*)(ws + (size_t)R * 4096 * 2); // [R,1024]
    ushort_t* s2   = (ushort_t*)(ws + (size_t)R * 5120 * 2); // [R,1024]
    ushort_t* xb   = (ushort_t*)(ws + (size_t)R * 6144 * 2); // [R,1024]
    ushort_t* wq   = (ushort_t*)(ws + (size_t)R * 7168 * 2);
    ushort_t* wo   = wq + WQKV_N;
    ushort_t* w1   = wo + WOUT_N;
    ushort_t* w2   = w1 + WFF1_N;

    f2b_kernel<<<WQKV_N / 1024, 256, 0, stream>>>(wqkv_f, wq);
    f2b_kernel<<<WOUT_N / 1024, 256, 0, stream>>>(wout_f, wo);
    f2b_kernel<<<WFF1_N / 1024, 256, 0, stream>>>(wff1_f, w1);
    f2b_kernel<<<WFF2_N / 1024, 256, 0, stream>>>(wff2_f, w2);

    for (int c = 0; c < nc; ++c) {
        const float* xc = x + (size_t)c * R * H_;
        float* oc = out + (size_t)c * R * H_;
        f2b_kernel<<<(R * H_) / 1024, 256, 0, stream>>>(xc, xb);
        // qkv = x @ Wqkv^T + b
        gemm_bt<0, float><<<dim3(24, R / 128), 256, 0, stream>>>(xb, wq, bqkv, (const float*)nullptr, qkv, 3072, 1024);
        // windowed attention
        attn_kernel<<<(R / 7) * 16, 64, 0, stream>>>(qkv, obuf);
        // s1 = x + o @ Wout^T + b   (residual in fp32 from original x)
        gemm_bt<2, float><<<dim3(8, R / 128), 256, 0, stream>>>(obuf, wo, bout, xc, ybuf, 1024, 1024);
        // y = LN1(s1), in place
        ln_kernel<ushort_t><<<R, 256, 0, stream>>>(ybuf, ybuf, ln1g, ln1b);
        // ff = relu(y @ W1^T + b1)
        gemm_bt<1, float><<<dim3(32, R / 128), 256, 0, stream>>>(ybuf, w1, bff1, (const float*)nullptr, ff, 4096, 1024);
        // s2 = y + ff @ W2^T + b2
        gemm_bt<2, ushort_t><<<dim3(8, R / 128), 256, 0, stream>>>(ff, w2, bff2, ybuf, s2, 1024, 4096);
        // out = LN2(s2), fp32
        ln_kernel<float><<<R, 256, 0, stream>>>(s2, oc, ln2g, ln2b);
    }
}

// Round 2
// 1136.126 us; speedup vs baseline: 1.0348x; 1.0348x over previous
//
#include <hip/hip_runtime.h>

typedef unsigned short ushort_t;
typedef __attribute__((ext_vector_type(8))) short short8;
typedef __attribute__((ext_vector_type(4))) float f32x4;

#define MTOT 28672   // B*S = 8*3584
#define H_   1024

static __device__ __forceinline__ float b2f(ushort_t u) {
    return __uint_as_float(((unsigned)u) << 16);
}
static __device__ __forceinline__ ushort_t f2b(float f) {
    unsigned u = __float_as_uint(f);
    u += 0x7fffu + ((u >> 16) & 1u);
    return (ushort_t)(u >> 16);
}
static __device__ __forceinline__ float ld_res(const float* p, long i) { return p[i]; }
static __device__ __forceinline__ float ld_res(const ushort_t* p, long i) { return b2f(p[i]); }

#define GLOAD(src, dst) __builtin_amdgcn_global_load_lds( \
    (const __attribute__((address_space(1))) void*)(src), \
    (__attribute__((address_space(3))) void*)(dst), 16, 0, 0)

// ---------------- fp32 -> bf16 conversion (n % 1024 == 0), 4 elems/thread ----------------
__global__ __launch_bounds__(256)
void f2b_kernel(const float* __restrict__ in, ushort_t* __restrict__ out)
{
    size_t i = (size_t)blockIdx.x * 256 + threadIdx.x;
    float4 v = ((const float4*)in)[i];
    ushort4 o;
    o.x = f2b(v.x); o.y = f2b(v.y); o.z = f2b(v.z); o.w = f2b(v.w);
    ((ushort4*)out)[i] = o;
}

// ---------------- bf16 GEMM v2: BM=128 BN=256 BK=32, 8 waves, counted-vmcnt pipeline ------
// A [M,K] bf16 rm, Bt [N,K] bf16 rm. M%128==0, N%256==0, K%32==0, K>=64.
// LDS: As[2] (A depth-1) + Bs[3] (B depth-2) = 64 KB. XOR-swizzled chunk layout:
//   chunk of (row r, kg) stored in super-row sr=r>>1 at pos = (((r&1)<<2)|kg) ^ (sr&7)
//   -> ds_read_b128 per quarter-wave spreads all 8 bank groups (2-way = free).
// Staging: top of tile t issues A(t+1), B(t+2); boundary wait = vmcnt(2) (B(t+1) in flight).
template<int EPI, typename ResT>
__global__ __launch_bounds__(512, 2)
void gemm_bt(const ushort_t* __restrict__ A, const ushort_t* __restrict__ Bt,
             const float* __restrict__ bias, const ResT* __restrict__ Res,
             ushort_t* __restrict__ C, int N, int K, int GX)
{
    __shared__ __align__(16) ushort_t As[2][128 * 32];   // 16 KB
    __shared__ __align__(16) ushort_t Bs[3][256 * 32];   // 48 KB
    const int tid  = threadIdx.x;
    const int wave = tid >> 6;
    const int lane = tid & 63;
    const int wm = wave >> 2, wn = wave & 3;   // 2x4 waves, 64x64 each
    const int fr = lane & 15, kg = lane >> 4;

    // bijective XCD-chunked swizzle (m204 form)
    const int nwg = gridDim.x;
    const int xcd = blockIdx.x & 7, ofs = blockIdx.x >> 3;
    const int q8 = nwg >> 3, r8 = nwg & 7;
    const int wg = (xcd < r8 ? xcd * (q8 + 1) : r8 * (q8 + 1) + (xcd - r8) * q8) + ofs;
    const long row0 = (long)(wg / GX) * 128;
    const long col0 = (long)(wg % GX) * 256;

    const int NT = K >> 5;

    // ---- staging source pointers (per-lane pre-swizzled global addresses) ----
    // A tile: 128 rows x 32 k = 512 chunks, 1 load/thread
    const ushort_t* pA;
    {
        int sr = tid >> 3, pos = tid & 7;
        int c = pos ^ (sr & 7);
        int r = sr * 2 + (c >> 2), kk = c & 3;
        pA = A + (row0 + r) * (size_t)K + kk * 8;
    }
    // B tile: 256 rows x 32 k = 1024 chunks, 2 loads/thread
    const ushort_t *pB0, *pB1;
    {
        int u = tid;
        int sr = u >> 3, pos = u & 7;
        int c = pos ^ (sr & 7);
        pB0 = Bt + (col0 + sr * 2 + (c >> 2)) * (size_t)K + (c & 3) * 8;
        u = tid + 512;
        sr = u >> 3; pos = u & 7;
        c = pos ^ (sr & 7);
        pB1 = Bt + (col0 + sr * 2 + (c >> 2)) * (size_t)K + (c & 3) * 8;
    }
    // LDS dest bases (wave-uniform; lane lands at +lane*16B)
    ushort_t* dA  = &As[0][0] + wave * 512;
    ushort_t* dB0 = &Bs[0][0] + wave * 512;
    ushort_t* dB1 = &Bs[0][0] + 4096 + wave * 512;

    // prologue: A(0)->As[0], B(0)->Bs[0], B(1)->Bs[1]  (oldest-first order matters for vmcnt)
    GLOAD(pA, dA);
    GLOAD(pB0, dB0);
    GLOAD(pB1, dB1);
    GLOAD(pB0 + 32, dB0 + 8192);
    GLOAD(pB1 + 32, dB1 + 8192);

    // per-lane ds_read byte offset within a 16-row frag block
    const int laneoff = (fr >> 1) * 128 + (((((fr & 1) << 2) | kg) ^ ((fr >> 1) & 7)) << 4);

    f32x4 acc[4][4] = {};

    for (int t = 0; t < NT; ++t) {
        if (t + 1 < NT) { asm volatile("s_waitcnt vmcnt(2)" ::: "memory"); }
        else            { asm volatile("s_waitcnt vmcnt(0)" ::: "memory"); }
        __builtin_amdgcn_s_barrier();
        // stage A(t+1) then B(t+2)  (A older than B in issue order)
        if (t + 1 < NT)
            GLOAD(pA + (size_t)(t + 1) * 32, dA + ((t + 1) & 1) * 4096);
        if (t + 2 < NT) {
            GLOAD(pB0 + (size_t)(t + 2) * 32, dB0 + ((t + 2) % 3) * 8192);
            GLOAD(pB1 + (size_t)(t + 2) * 32, dB1 + ((t + 2) % 3) * 8192);
        }
        const char* Ab = (const char*)&As[0][0] + (t & 1) * 8192  + wm * 4096;
        const char* Bb = (const char*)&Bs[0][0] + (t % 3) * 16384 + wn * 4096;
        short8 a0 = *(const short8*)(Ab + 0 * 1024 + laneoff);
        short8 a1 = *(const short8*)(Ab + 1 * 1024 + laneoff);
        short8 a2 = *(const short8*)(Ab + 2 * 1024 + laneoff);
        short8 a3 = *(const short8*)(Ab + 3 * 1024 + laneoff);
        short8 b0 = *(const short8*)(Bb + 0 * 1024 + laneoff);
        short8 b1 = *(const short8*)(Bb + 1 * 1024 + laneoff);
        short8 b2 = *(const short8*)(Bb + 2 * 1024 + laneoff);
        short8 b3 = *(const short8*)(Bb + 3 * 1024 + laneoff);
        __builtin_amdgcn_s_setprio(1);
        acc[0][0] = __builtin_amdgcn_mfma_f32_16x16x32_bf16(a0, b0, acc[0][0], 0, 0, 0);
        acc[0][1] = __builtin_amdgcn_mfma_f32_16x16x32_bf16(a0, b1, acc[0][1], 0, 0, 0);
        acc[0][2] = __builtin_amdgcn_mfma_f32_16x16x32_bf16(a0, b2, acc[0][2], 0, 0, 0);
        acc[0][3] = __builtin_amdgcn_mfma_f32_16x16x32_bf16(a0, b3, acc[0][3], 0, 0, 0);
        acc[1][0] = __builtin_amdgcn_mfma_f32_16x16x32_bf16(a1, b0, acc[1][0], 0, 0, 0);
        acc[1][1] = __builtin_amdgcn_mfma_f32_16x16x32_bf16(a1, b1, acc[1][1], 0, 0, 0);
        acc[1][2] = __builtin_amdgcn_mfma_f32_16x16x32_bf16(a1, b2, acc[1][2], 0, 0, 0);
        acc[1][3] = __builtin_amdgcn_mfma_f32_16x16x32_bf16(a1, b3, acc[1][3], 0, 0, 0);
        acc[2][0] = __builtin_amdgcn_mfma_f32_16x16x32_bf16(a2, b0, acc[2][0], 0, 0, 0);
        acc[2][1] = __builtin_amdgcn_mfma_f32_16x16x32_bf16(a2, b1, acc[2][1], 0, 0, 0);
        acc[2][2] = __builtin_amdgcn_mfma_f32_16x16x32_bf16(a2, b2, acc[2][2], 0, 0, 0);
        acc[2][3] = __builtin_amdgcn_mfma_f32_16x16x32_bf16(a2, b3, acc[2][3], 0, 0, 0);
        acc[3][0] = __builtin_amdgcn_mfma_f32_16x16x32_bf16(a3, b0, acc[3][0], 0, 0, 0);
        acc[3][1] = __builtin_amdgcn_mfma_f32_16x16x32_bf16(a3, b1, acc[3][1], 0, 0, 0);
        acc[3][2] = __builtin_amdgcn_mfma_f32_16x16x32_bf16(a3, b2, acc[3][2], 0, 0, 0);
        acc[3][3] = __builtin_amdgcn_mfma_f32_16x16x32_bf16(a3, b3, acc[3][3], 0, 0, 0);
        __builtin_amdgcn_s_setprio(0);
    }

    // epilogue: C/D layout col=lane&15, row=(lane>>4)*4+reg
    #pragma unroll
    for (int n = 0; n < 4; ++n) {
        long cg = col0 + wn * 64 + n * 16 + fr;
        float bv = bias[cg];
        #pragma unroll
        for (int m = 0; m < 4; ++m) {
            long rbase = row0 + wm * 64 + m * 16 + kg * 4;
            #pragma unroll
            for (int qq = 0; qq < 4; ++qq) {
                float v = acc[m][n][qq] + bv;
                if constexpr (EPI == 1) v = fmaxf(v, 0.f);
                if constexpr (EPI == 2) v += ld_res(Res, (rbase + qq) * (long)N + cg);
                C[(rbase + qq) * (long)N + cg] = f2b(v);
            }
        }
    }
}

// ---------------- per-(window,head) attention: q,k,v [7,64]; one wave per block ----------------
__global__ __launch_bounds__(64)
void attn_kernel(const ushort_t* __restrict__ qkv, ushort_t* __restrict__ o)
{
    const int bid  = blockIdx.x;
    const int win  = bid >> 4;
    const int head = bid & 15;
    const int lane = threadIdx.x;
    __shared__ float qs[7][64], ks[7][64], vs[7][64];
    __shared__ float sc[7][8], pr[7][8];
    const long t0 = (long)win * 7;
    const ushort_t* base = qkv + t0 * 3072 + head * 64 + lane;
    #pragma unroll
    for (int i = 0; i < 7; ++i) {
        qs[i][lane] = b2f(base[(long)i * 3072]);
        ks[i][lane] = b2f(base[(long)i * 3072 + 1024]);
        vs[i][lane] = b2f(base[(long)i * 3072 + 2048]);
    }
    __syncthreads();
    if (lane < 49) {
        int i = lane / 7, j = lane % 7;
        float a = 0.f;
        #pragma unroll
        for (int d = 0; d < 64; ++d) a += qs[i][d] * ks[j][d];
        sc[i][j] = a * 0.125f;
    }
    __syncthreads();
    if (lane < 7) {
        float m = sc[lane][0];
        #pragma unroll
        for (int j = 1; j < 7; ++j) m = fmaxf(m, sc[lane][j]);
        float e[7], den = 0.f;
        #pragma unroll
        for (int j = 0; j < 7; ++j) { e[j] = __expf(sc[lane][j] - m); den += e[j]; }
        float inv = 1.f / den;
        #pragma unroll
        for (int j = 0; j < 7; ++j) pr[lane][j] = e[j] * inv;
    }
    __syncthreads();
    ushort_t* ob = o + t0 * 1024 + head * 64 + lane;
    #pragma unroll
    for (int i = 0; i < 7; ++i) {
        float a = 0.f;
        #pragma unroll
        for (int j = 0; j < 7; ++j) a += pr[i][j] * vs[j][lane];
        ob[(long)i * 1024] = f2b(a);
    }
}

// ---------------- row LayerNorm over H=1024; 256 threads, 4 elems/thread ----------------
template<typename OutT>
__global__ __launch_bounds__(256)
void ln_kernel(const ushort_t* in, OutT* out,
               const float* __restrict__ g, const float* __restrict__ b)
{
    const long row = blockIdx.x;
    const int tid = threadIdx.x;
    const ushort_t* p = in + row * H_;
    ushort4 raw = ((const ushort4*)p)[tid];
    float x0 = b2f(raw.x), x1 = b2f(raw.y), x2 = b2f(raw.z), x3 = b2f(raw.w);
    float s  = x0 + x1 + x2 + x3;
    float ss = x0*x0 + x1*x1 + x2*x2 + x3*x3;
    #pragma unroll
    for (int off = 32; off > 0; off >>= 1) {
        s  += __shfl_down(s,  off, 64);
        ss += __shfl_down(ss, off, 64);
    }
    __shared__ float rs[4], rss[4];
    const int wave = tid >> 6, lane = tid & 63;
    if (lane == 0) { rs[wave] = s; rss[wave] = ss; }
    __syncthreads();
    float S  = rs[0] + rs[1] + rs[2] + rs[3];
    float SS = rss[0] + rss[1] + rss[2] + rss[3];
    float mean = S * (1.f / 1024.f);
    float var  = SS * (1.f / 1024.f) - mean * mean;
    float inv  = rsqrtf(var + 1e-5f);
    float4 gv = ((const float4*)g)[tid];
    float4 bv = ((const float4*)b)[tid];
    float y0 = (x0 - mean) * inv * gv.x + bv.x;
    float y1 = (x1 - mean) * inv * gv.y + bv.y;
    float y2 = (x2 - mean) * inv * gv.z + bv.z;
    float y3 = (x3 - mean) * inv * gv.w + bv.w;
    if constexpr (sizeof(OutT) == 2) {
        ushort4 ov; ov.x = f2b(y0); ov.y = f2b(y1); ov.z = f2b(y2); ov.w = f2b(y3);
        ((ushort4*)out)[row * 256 + tid] = ov;
    } else {
        float4 ov; ov.x = y0; ov.y = y1; ov.z = y2; ov.w = y3;
        ((float4*)out)[row * 256 + tid] = ov;
    }
}

// ---------------- launch ----------------
extern "C" void kernel_launch(void* const* d_in, const int* in_sizes, int n_in,
                              void* d_out, int out_size, void* d_ws, size_t ws_size,
                              hipStream_t stream)
{
    const float* x      = (const float*)d_in[0];
    const float* wqkv_f = (const float*)d_in[1];
    const float* bqkv   = (const float*)d_in[2];
    const float* wout_f = (const float*)d_in[3];
    const float* bout   = (const float*)d_in[4];
    const float* ln1g   = (const float*)d_in[5];
    const float* ln1b   = (const float*)d_in[6];
    const float* ln2g   = (const float*)d_in[7];
    const float* ln2b   = (const float*)d_in[8];
    const float* wff1_f = (const float*)d_in[9];
    const float* bff1   = (const float*)d_in[10];
    const float* wff2_f = (const float*)d_in[11];
    const float* bff2   = (const float*)d_in[12];
    float* out = (float*)d_out;

    const size_t WQKV_N = 3072l * 1024, WOUT_N = 1024l * 1024;
    const size_t WFF1_N = 4096l * 1024, WFF2_N = 1024l * 4096;
    const size_t welems = WQKV_N + WOUT_N + WFF1_N + WFF2_N;

    // chunk rows R: multiple of lcm(7,256)=1792; per-chunk arena = R*14336 B + weights
    int nc = 1;
    while (nc < 16 && (size_t)(MTOT / nc) * 14336 + welems * 2 > ws_size) nc <<= 1;
    const long R = MTOT / nc;

    char* ws = (char*)d_ws;
    ushort_t* qkv  = (ushort_t*)ws;                          // [R,3072]
    ushort_t* obuf = (ushort_t*)(ws + (size_t)R * 3072 * 2); // [R,1024]
    ushort_t* ff   = qkv;                                    // [R,4096] reuses qkv+obuf
    ushort_t* ybuf = (ushort_t*)(ws + (size_t)R * 4096 * 2); // [R,1024]
    ushort_t* s2   = (ushort_t*)(ws + (size_t)R * 5120 * 2); // [R,1024]
    ushort_t* xb   = (ushort_t*)(ws + (size_t)R * 6144 * 2); // [R,1024]
    ushort_t* wq   = (ushort_t*)(ws + (size_t)R * 7168 * 2);
    ushort_t* wo   = wq + WQKV_N;
    ushort_t* w1   = wo + WOUT_N;
    ushort_t* w2   = w1 + WFF1_N;

    f2b_kernel<<<WQKV_N / 1024, 256, 0, stream>>>(wqkv_f, wq);
    f2b_kernel<<<WOUT_N / 1024, 256, 0, stream>>>(wout_f, wo);
    f2b_kernel<<<WFF1_N / 1024, 256, 0, stream>>>(wff1_f, w1);
    f2b_kernel<<<WFF2_N / 1024, 256, 0, stream>>>(wff2_f, w2);

    for (int c = 0; c < nc; ++c) {
        const float* xc = x + (size_t)c * R * H_;
        float* oc = out + (size_t)c * R * H_;
        const int GY = R / 128;
        f2b_kernel<<<(R * H_) / 1024, 256, 0, stream>>>(xc, xb);
        // qkv = x @ Wqkv^T + b
        gemm_bt<0, float><<<12 * GY, 512, 0, stream>>>(xb, wq, bqkv, (const float*)nullptr, qkv, 3072, 1024, 12);
        // windowed attention
        attn_kernel<<<(R / 7) * 16, 64, 0, stream>>>(qkv, obuf);
        // s1 = x + o @ Wout^T + b   (residual in fp32 from original x)
        gemm_bt<2, float><<<4 * GY, 512, 0, stream>>>(obuf, wo, bout, xc, ybuf, 1024, 1024, 4);
        // y = LN1(s1), in place
        ln_kernel<ushort_t><<<R, 256, 0, stream>>>(ybuf, ybuf, ln1g, ln1b);
        // ff = relu(y @ W1^T + b1)
        gemm_bt<1, float><<<16 * GY, 512, 0, stream>>>(ybuf, w1, bff1, (const float*)nullptr, ff, 4096, 1024, 16);
        // s2 = y + ff @ W2^T + b2
        gemm_bt<2, ushort_t><<<4 * GY, 512, 0, stream>>>(ff, w2, bff2, ybuf, s2, 1024, 4096, 4);
        // out = LN2(s2), fp32
        ln_kernel<float><<<R, 256, 0, stream>>>(s2, oc, ln2g, ln2b);
    }
}

// Round 3
// 1047.970 us; speedup vs baseline: 1.1219x; 1.0841x over previous
//
#include <hip/hip_runtime.h>

typedef unsigned short ushort_t;
typedef __attribute__((ext_vector_type(8))) short short8;
typedef __attribute__((ext_vector_type(4))) float f32x4;

#define MTOT 28672   // B*S = 8*3584
#define H_   1024

static __device__ __forceinline__ float b2f(ushort_t u) {
    return __uint_as_float(((unsigned)u) << 16);
}
static __device__ __forceinline__ ushort_t f2b(float f) {
    unsigned u = __float_as_uint(f);
    u += 0x7fffu + ((u >> 16) & 1u);
    return (ushort_t)(u >> 16);
}
static __device__ __forceinline__ float ld_res(const float* p, long i) { return p[i]; }
static __device__ __forceinline__ float ld_res(const ushort_t* p, long i) { return b2f(p[i]); }

#define GLOAD(src, dst) __builtin_amdgcn_global_load_lds( \
    (const __attribute__((address_space(1))) void*)(src), \
    (__attribute__((address_space(3))) void*)(dst), 16, 0, 0)
#define MFMA16(a, b, c) __builtin_amdgcn_mfma_f32_16x16x32_bf16(a, b, c, 0, 0, 0)

// ---------------- fp32 -> bf16 conversion (n % 1024 == 0), 4 elems/thread ----------------
__global__ __launch_bounds__(256)
void f2b_kernel(const float* __restrict__ in, ushort_t* __restrict__ out)
{
    size_t i = (size_t)blockIdx.x * 256 + threadIdx.x;
    float4 v = ((const float4*)in)[i];
    ushort4 o;
    o.x = f2b(v.x); o.y = f2b(v.y); o.z = f2b(v.z); o.w = f2b(v.w);
    ((ushort4*)out)[i] = o;
}

// ---------------- bf16 GEMM v3: BM=BN=256, BK=64, 8 waves (2m x 4n, 128x64 each) ----------
// A [M,K] bf16 rm, Bt [N,K] bf16 rm. M%256==0, N%256==0, K%64==0, K>=128.
// LDS 128 KB: lds[buf 2][region 4][16 KB], region: 0=A-Khalf0, 1=B-Kh0, 2=A-Kh1, 3=B-Kh1.
// Region layout: row r (256) x 4 chunks(16B); chunk kk stored at pos = kk ^ ((r>>1)&3),
// byte = r*64 + pos*16 -> 64 lanes of a frag-read spread 8 bank-groups evenly (0 conflicts).
// Schedule per K64-tile: 4 phases {barrier; ds_read 4|8; 2x global_load_lds prefetch;
// setprio(1) 16 MFMA setprio(0)}, counted s_waitcnt vmcnt(4) at phases 0,2 (1 tile in flight).
template<int EPI, typename ResT>
__global__ __launch_bounds__(512, 1)
void gemm_bt(const ushort_t* __restrict__ A, const ushort_t* __restrict__ Bt,
             const float* __restrict__ bias, const ResT* __restrict__ Res,
             ushort_t* __restrict__ C, int N, int K, int GX)
{
    __shared__ __align__(16) ushort_t lds[2][4][8192];
    const int tid  = threadIdx.x;
    const int wave = tid >> 6;
    const int lane = tid & 63;
    const int wm = wave >> 2, wn = wave & 3;   // 2x4 waves, each 128 rows x 64 cols
    const int fr = lane & 15, kg = lane >> 4;

    // bijective XCD-chunked swizzle (m204 form)
    const int nwg = gridDim.x;
    const int xcd = blockIdx.x & 7, ofs = blockIdx.x >> 3;
    const int q8 = nwg >> 3, r8 = nwg & 7;
    const int wg = (xcd < r8 ? xcd * (q8 + 1) : r8 * (q8 + 1) + (xcd - r8) * q8) + ofs;
    const long row0 = (long)(wg / GX) * 256;
    const long col0 = (long)(wg % GX) * 256;

    const int NT = K >> 6;

    // ---- staging: per region 1024 chunks = 512 threads x 2 rounds (round1 = +128 rows) ----
    const int sr_ = tid >> 2;
    const int kk_ = (tid & 3) ^ ((sr_ >> 1) & 3);
    const ushort_t* pa = A  + (row0 + sr_) * (size_t)K + kk_ * 8;
    const ushort_t* pb = Bt + (col0 + sr_) * (size_t)K + kk_ * 8;
    const size_t rstep = (size_t)128 * K;

    // prologue: tile 0, regions in vmcnt order 0,1,2,3
    {
        ushort_t* d0 = &lds[0][0][0] + wave * 512;
        ushort_t* d1 = &lds[0][1][0] + wave * 512;
        ushort_t* d2 = &lds[0][2][0] + wave * 512;
        ushort_t* d3 = &lds[0][3][0] + wave * 512;
        GLOAD(pa,            d0); GLOAD(pa + rstep,      d0 + 4096);
        GLOAD(pb,            d1); GLOAD(pb + rstep,      d1 + 4096);
        GLOAD(pa + 32,       d2); GLOAD(pa + 32 + rstep, d2 + 4096);
        GLOAD(pb + 32,       d3); GLOAD(pb + 32 + rstep, d3 + 4096);
    }

    // per-lane ds_read byte offsets
    const int pos2  = kg ^ ((fr >> 1) & 3);
    const int abase = (wm * 128 + fr) * 64 + pos2 * 16;   // + m*1024
    const int bbase = (wn * 64  + fr) * 64 + pos2 * 16;   // + n*1024

    f32x4 acc[8][4] = {};
    short8 av[4], bv[4];

    for (int t = 0; t < NT; ++t) {
        const int b = t & 1;
        const bool pf = (t + 1 < NT);
        const size_t go = (size_t)(t + 1) * 64;
        const char* rA0 = (const char*)&lds[b][0][0];
        const char* rB0 = (const char*)&lds[b][1][0];
        const char* rA1 = (const char*)&lds[b][2][0];
        const char* rB1 = (const char*)&lds[b][3][0];
        ushort_t* d0 = &lds[1 - b][0][0] + wave * 512;
        ushort_t* d1 = &lds[1 - b][1][0] + wave * 512;
        ushort_t* d2 = &lds[1 - b][2][0] + wave * 512;
        ushort_t* d3 = &lds[1 - b][3][0] + wave * 512;

        // ---- phase 0: Khalf0, m 0-3 ----
        asm volatile("s_waitcnt vmcnt(4)" ::: "memory");
        asm volatile("s_barrier" ::: "memory");
        #pragma unroll
        for (int i = 0; i < 4; ++i) av[i] = *(const short8*)(rA0 + abase + i * 1024);
        #pragma unroll
        for (int i = 0; i < 4; ++i) bv[i] = *(const short8*)(rB0 + bbase + i * 1024);
        if (pf) { GLOAD(pa + go, d0); GLOAD(pa + go + rstep, d0 + 4096); }
        __builtin_amdgcn_s_setprio(1);
        #pragma unroll
        for (int i = 0; i < 4; ++i)
            #pragma unroll
            for (int j = 0; j < 4; ++j) acc[i][j] = MFMA16(av[i], bv[j], acc[i][j]);
        __builtin_amdgcn_s_setprio(0);

        // ---- phase 1: Khalf0, m 4-7 (reuse bv) ----
        asm volatile("s_barrier" ::: "memory");
        #pragma unroll
        for (int i = 0; i < 4; ++i) av[i] = *(const short8*)(rA0 + abase + (4 + i) * 1024);
        if (pf) { GLOAD(pb + go, d1); GLOAD(pb + go + rstep, d1 + 4096); }
        __builtin_amdgcn_s_setprio(1);
        #pragma unroll
        for (int i = 0; i < 4; ++i)
            #pragma unroll
            for (int j = 0; j < 4; ++j) acc[4 + i][j] = MFMA16(av[i], bv[j], acc[4 + i][j]);
        __builtin_amdgcn_s_setprio(0);

        // ---- phase 2: Khalf1, m 0-3 ----
        if (pf) { asm volatile("s_waitcnt vmcnt(4)" ::: "memory"); }
        else    { asm volatile("s_waitcnt vmcnt(0)" ::: "memory"); }
        asm volatile("s_barrier" ::: "memory");
        #pragma unroll
        for (int i = 0; i < 4; ++i) av[i] = *(const short8*)(rA1 + abase + i * 1024);
        #pragma unroll
        for (int i = 0; i < 4; ++i) bv[i] = *(const short8*)(rB1 + bbase + i * 1024);
        if (pf) { GLOAD(pa + go + 32, d2); GLOAD(pa + go + 32 + rstep, d2 + 4096); }
        __builtin_amdgcn_s_setprio(1);
        #pragma unroll
        for (int i = 0; i < 4; ++i)
            #pragma unroll
            for (int j = 0; j < 4; ++j) acc[i][j] = MFMA16(av[i], bv[j], acc[i][j]);
        __builtin_amdgcn_s_setprio(0);

        // ---- phase 3: Khalf1, m 4-7 ----
        asm volatile("s_barrier" ::: "memory");
        #pragma unroll
        for (int i = 0; i < 4; ++i) av[i] = *(const short8*)(rA1 + abase + (4 + i) * 1024);
        if (pf) { GLOAD(pb + go + 32, d3); GLOAD(pb + go + 32 + rstep, d3 + 4096); }
        __builtin_amdgcn_s_setprio(1);
        #pragma unroll
        for (int i = 0; i < 4; ++i)
            #pragma unroll
            for (int j = 0; j < 4; ++j) acc[4 + i][j] = MFMA16(av[i], bv[j], acc[4 + i][j]);
        __builtin_amdgcn_s_setprio(0);
    }

    // epilogue: C/D layout col=lane&15, row=(lane>>4)*4+reg
    #pragma unroll
    for (int n = 0; n < 4; ++n) {
        long cg = col0 + wn * 64 + n * 16 + fr;
        float bvs = bias[cg];
        #pragma unroll
        for (int m = 0; m < 8; ++m) {
            long rbase = row0 + wm * 128 + m * 16 + kg * 4;
            #pragma unroll
            for (int qq = 0; qq < 4; ++qq) {
                float v = acc[m][n][qq] + bvs;
                if constexpr (EPI == 1) v = fmaxf(v, 0.f);
                if constexpr (EPI == 2) v += ld_res(Res, (rbase + qq) * (long)N + cg);
                C[(rbase + qq) * (long)N + cg] = f2b(v);
            }
        }
    }
}

// ---------------- per-(window,head) attention: q,k,v [7,64]; one wave per block ----------------
__global__ __launch_bounds__(64)
void attn_kernel(const ushort_t* __restrict__ qkv, ushort_t* __restrict__ o)
{
    const int bid  = blockIdx.x;
    const int win  = bid >> 4;
    const int head = bid & 15;
    const int lane = threadIdx.x;
    __shared__ float qs[7][64], ks[7][64], vs[7][64];
    __shared__ float sc[7][8], pr[7][8];
    const long t0 = (long)win * 7;
    const ushort_t* base = qkv + t0 * 3072 + head * 64 + lane;
    #pragma unroll
    for (int i = 0; i < 7; ++i) {
        qs[i][lane] = b2f(base[(long)i * 3072]);
        ks[i][lane] = b2f(base[(long)i * 3072 + 1024]);
        vs[i][lane] = b2f(base[(long)i * 3072 + 2048]);
    }
    __syncthreads();
    if (lane < 49) {
        int i = lane / 7, j = lane % 7;
        float a = 0.f;
        #pragma unroll
        for (int d = 0; d < 64; ++d) a += qs[i][d] * ks[j][d];
        sc[i][j] = a * 0.125f;
    }
    __syncthreads();
    if (lane < 7) {
        float m = sc[lane][0];
        #pragma unroll
        for (int j = 1; j < 7; ++j) m = fmaxf(m, sc[lane][j]);
        float e[7], den = 0.f;
        #pragma unroll
        for (int j = 0; j < 7; ++j) { e[j] = __expf(sc[lane][j] - m); den += e[j]; }
        float inv = 1.f / den;
        #pragma unroll
        for (int j = 0; j < 7; ++j) pr[lane][j] = e[j] * inv;
    }
    __syncthreads();
    ushort_t* ob = o + t0 * 1024 + head * 64 + lane;
    #pragma unroll
    for (int i = 0; i < 7; ++i) {
        float a = 0.f;
        #pragma unroll
        for (int j = 0; j < 7; ++j) a += pr[i][j] * vs[j][lane];
        ob[(long)i * 1024] = f2b(a);
    }
}

// ---------------- row LayerNorm over H=1024; 256 threads, 4 elems/thread ----------------
template<typename OutT>
__global__ __launch_bounds__(256)
void ln_kernel(const ushort_t* in, OutT* out,
               const float* __restrict__ g, const float* __restrict__ b)
{
    const long row = blockIdx.x;
    const int tid = threadIdx.x;
    const ushort_t* p = in + row * H_;
    ushort4 raw = ((const ushort4*)p)[tid];
    float x0 = b2f(raw.x), x1 = b2f(raw.y), x2 = b2f(raw.z), x3 = b2f(raw.w);
    float s  = x0 + x1 + x2 + x3;
    float ss = x0*x0 + x1*x1 + x2*x2 + x3*x3;
    #pragma unroll
    for (int off = 32; off > 0; off >>= 1) {
        s  += __shfl_down(s,  off, 64);
        ss += __shfl_down(ss, off, 64);
    }
    __shared__ float rs[4], rss[4];
    const int wave = tid >> 6, lane = tid & 63;
    if (lane == 0) { rs[wave] = s; rss[wave] = ss; }
    __syncthreads();
    float S  = rs[0] + rs[1] + rs[2] + rs[3];
    float SS = rss[0] + rss[1] + rss[2] + rss[3];
    float mean = S * (1.f / 1024.f);
    float var  = SS * (1.f / 1024.f) - mean * mean;
    float inv  = rsqrtf(var + 1e-5f);
    float4 gv = ((const float4*)g)[tid];
    float4 bvv = ((const float4*)b)[tid];
    float y0 = (x0 - mean) * inv * gv.x + bvv.x;
    float y1 = (x1 - mean) * inv * gv.y + bvv.y;
    float y2 = (x2 - mean) * inv * gv.z + bvv.z;
    float y3 = (x3 - mean) * inv * gv.w + bvv.w;
    if constexpr (sizeof(OutT) == 2) {
        ushort4 ov; ov.x = f2b(y0); ov.y = f2b(y1); ov.z = f2b(y2); ov.w = f2b(y3);
        ((ushort4*)out)[row * 256 + tid] = ov;
    } else {
        float4 ov; ov.x = y0; ov.y = y1; ov.z = y2; ov.w = y3;
        ((float4*)out)[row * 256 + tid] = ov;
    }
}

// ---------------- launch ----------------
extern "C" void kernel_launch(void* const* d_in, const int* in_sizes, int n_in,
                              void* d_out, int out_size, void* d_ws, size_t ws_size,
                              hipStream_t stream)
{
    const float* x      = (const float*)d_in[0];
    const float* wqkv_f = (const float*)d_in[1];
    const float* bqkv   = (const float*)d_in[2];
    const float* wout_f = (const float*)d_in[3];
    const float* bout   = (const float*)d_in[4];
    const float* ln1g   = (const float*)d_in[5];
    const float* ln1b   = (const float*)d_in[6];
    const float* ln2g   = (const float*)d_in[7];
    const float* ln2b   = (const float*)d_in[8];
    const float* wff1_f = (const float*)d_in[9];
    const float* bff1   = (const float*)d_in[10];
    const float* wff2_f = (const float*)d_in[11];
    const float* bff2   = (const float*)d_in[12];
    float* out = (float*)d_out;

    const size_t WQKV_N = 3072l * 1024, WOUT_N = 1024l * 1024;
    const size_t WFF1_N = 4096l * 1024, WFF2_N = 1024l * 4096;
    const size_t welems = WQKV_N + WOUT_N + WFF1_N + WFF2_N;

    // chunk rows R: multiple of lcm(7,256)=1792; per-chunk arena = R*14336 B + weights
    int nc = 1;
    while (nc < 16 && (size_t)(MTOT / nc) * 14336 + welems * 2 > ws_size) nc <<= 1;
    const long R = MTOT / nc;

    char* ws = (char*)d_ws;
    ushort_t* qkv  = (ushort_t*)ws;                          // [R,3072]
    ushort_t* obuf = (ushort_t*)(ws + (size_t)R * 3072 * 2); // [R,1024]
    ushort_t* ff   = qkv;                                    // [R,4096] reuses qkv+obuf
    ushort_t* ybuf = (ushort_t*)(ws + (size_t)R * 4096 * 2); // [R,1024]
    ushort_t* s2   = (ushort_t*)(ws + (size_t)R * 5120 * 2); // [R,1024]
    ushort_t* xb   = (ushort_t*)(ws + (size_t)R * 6144 * 2); // [R,1024]
    ushort_t* wq   = (ushort_t*)(ws + (size_t)R * 7168 * 2);
    ushort_t* wo   = wq + WQKV_N;
    ushort_t* w1   = wo + WOUT_N;
    ushort_t* w2   = w1 + WFF1_N;

    f2b_kernel<<<WQKV_N / 1024, 256, 0, stream>>>(wqkv_f, wq);
    f2b_kernel<<<WOUT_N / 1024, 256, 0, stream>>>(wout_f, wo);
    f2b_kernel<<<WFF1_N / 1024, 256, 0, stream>>>(wff1_f, w1);
    f2b_kernel<<<WFF2_N / 1024, 256, 0, stream>>>(wff2_f, w2);

    for (int c = 0; c < nc; ++c) {
        const float* xc = x + (size_t)c * R * H_;
        float* oc = out + (size_t)c * R * H_;
        const int GY = R / 256;
        f2b_kernel<<<(R * H_) / 1024, 256, 0, stream>>>(xc, xb);
        // qkv = x @ Wqkv^T + b
        gemm_bt<0, float><<<12 * GY, 512, 0, stream>>>(xb, wq, bqkv, (const float*)nullptr, qkv, 3072, 1024, 12);
        // windowed attention
        attn_kernel<<<(R / 7) * 16, 64, 0, stream>>>(qkv, obuf);
        // s1 = x + o @ Wout^T + b   (residual in fp32 from original x)
        gemm_bt<2, float><<<4 * GY, 512, 0, stream>>>(obuf, wo, bout, xc, ybuf, 1024, 1024, 4);
        // y = LN1(s1), in place
        ln_kernel<ushort_t><<<R, 256, 0, stream>>>(ybuf, ybuf, ln1g, ln1b);
        // ff = relu(y @ W1^T + b1)
        gemm_bt<1, float><<<16 * GY, 512, 0, stream>>>(ybuf, w1, bff1, (const float*)nullptr, ff, 4096, 1024, 16);
        // s2 = y + ff @ W2^T + b2
        gemm_bt<2, ushort_t><<<4 * GY, 512, 0, stream>>>(ff, w2, bff2, ybuf, s2, 1024, 4096, 4);
        // out = LN2(s2), fp32
        ln_kernel<float><<<R, 256, 0, stream>>>(s2, oc, ln2g, ln2b);
    }
}

// Round 4
// 963.943 us; speedup vs baseline: 1.2197x; 1.0872x over previous
//
#include <hip/hip_runtime.h>

typedef unsigned short ushort_t;
typedef __attribute__((ext_vector_type(8))) short short8;
typedef __attribute__((ext_vector_type(4))) float f32x4;

#define MTOT 28672   // B*S = 8*3584
#define H_   1024

static __device__ __forceinline__ float b2f(ushort_t u) {
    return __uint_as_float(((unsigned)u) << 16);
}
static __device__ __forceinline__ ushort_t f2b(float f) {
    unsigned u = __float_as_uint(f);
    u += 0x7fffu + ((u >> 16) & 1u);
    return (ushort_t)(u >> 16);
}

#define GLOAD(src, dst) __builtin_amdgcn_global_load_lds( \
    (const __attribute__((address_space(1))) void*)(src), \
    (__attribute__((address_space(3))) void*)(dst), 16, 0, 0)
#define MFMA16(a, b, c) __builtin_amdgcn_mfma_f32_16x16x32_bf16(a, b, c, 0, 0, 0)

// ---------------- fp32 -> bf16 conversion (n % 1024 == 0), 4 elems/thread ----------------
__global__ __launch_bounds__(256)
void f2b_kernel(const float* __restrict__ in, ushort_t* __restrict__ out)
{
    size_t i = (size_t)blockIdx.x * 256 + threadIdx.x;
    float4 v = ((const float4*)in)[i];
    ushort4 o;
    o.x = f2b(v.x); o.y = f2b(v.y); o.z = f2b(v.z); o.w = f2b(v.w);
    ((ushort4*)out)[i] = o;
}

// ---------------- bf16 GEMM v4: BM=BN=256, BK=64, 8 waves; swapped-operand MFMA +
// LDS-transposed coalesced epilogue.
// A [M,K] bf16 rm, Bt [N,K] bf16 rm. M%256==0, N%256==0, K%64==0, K>=128.
// K-loop identical to v3 (counted vmcnt(4), 4 phases, XOR-swizzled staging).
// MFMA called as mfma(bv, av): lane (fr,kg) of frag (m,n) holds
//   C row = wm*128+m*16+fr, cols = wn*64+n*16+kg*4+{0..3}  (4 consecutive!)
// Epilogue: bias/relu/residual per-lane (float4-coalesced), pack 4 bf16 -> ds_write_b64
// into swizzled [256][512B] tile (chunk16 ^= row&31), read back 16B/lane with 4 lanes/row
// -> 64B-contiguous global stores.
template<int EPI, typename ResT>
__global__ __launch_bounds__(512, 1)
void gemm_bt(const ushort_t* __restrict__ A, const ushort_t* __restrict__ Bt,
             const float* __restrict__ bias, const ResT* __restrict__ Res,
             ushort_t* __restrict__ C, int N, int K, int GX)
{
    __shared__ __align__(16) ushort_t lds[2][4][8192];   // 128 KB
    const int tid  = threadIdx.x;
    const int wave = tid >> 6;
    const int lane = tid & 63;
    const int wm = wave >> 2, wn = wave & 3;   // 2x4 waves, each 128 rows x 64 cols
    const int fr = lane & 15, kg = lane >> 4;

    // bijective XCD-chunked swizzle (m204 form)
    const int nwg = gridDim.x;
    const int xcd = blockIdx.x & 7, ofs = blockIdx.x >> 3;
    const int q8 = nwg >> 3, r8 = nwg & 7;
    const int wg = (xcd < r8 ? xcd * (q8 + 1) : r8 * (q8 + 1) + (xcd - r8) * q8) + ofs;
    const long row0 = (long)(wg / GX) * 256;
    const long col0 = (long)(wg % GX) * 256;

    const int NT = K >> 6;

    // ---- staging: per region 1024 chunks = 512 threads x 2 rounds (round1 = +128 rows) ----
    const int sr_ = tid >> 2;
    const int kk_ = (tid & 3) ^ ((sr_ >> 1) & 3);
    const ushort_t* pa = A  + (row0 + sr_) * (size_t)K + kk_ * 8;
    const ushort_t* pb = Bt + (col0 + sr_) * (size_t)K + kk_ * 8;
    const size_t rstep = (size_t)128 * K;

    // prologue: tile 0, regions in vmcnt order 0,1,2,3
    {
        ushort_t* d0 = &lds[0][0][0] + wave * 512;
        ushort_t* d1 = &lds[0][1][0] + wave * 512;
        ushort_t* d2 = &lds[0][2][0] + wave * 512;
        ushort_t* d3 = &lds[0][3][0] + wave * 512;
        GLOAD(pa,            d0); GLOAD(pa + rstep,      d0 + 4096);
        GLOAD(pb,            d1); GLOAD(pb + rstep,      d1 + 4096);
        GLOAD(pa + 32,       d2); GLOAD(pa + 32 + rstep, d2 + 4096);
        GLOAD(pb + 32,       d3); GLOAD(pb + 32 + rstep, d3 + 4096);
    }

    // per-lane ds_read byte offsets
    const int pos2  = kg ^ ((fr >> 1) & 3);
    const int abase = (wm * 128 + fr) * 64 + pos2 * 16;   // + m*1024
    const int bbase = (wn * 64  + fr) * 64 + pos2 * 16;   // + n*1024

    f32x4 acc[8][4] = {};
    short8 av[4], bv[4];

    for (int t = 0; t < NT; ++t) {
        const int b = t & 1;
        const bool pf = (t + 1 < NT);
        const size_t go = (size_t)(t + 1) * 64;
        const char* rA0 = (const char*)&lds[b][0][0];
        const char* rB0 = (const char*)&lds[b][1][0];
        const char* rA1 = (const char*)&lds[b][2][0];
        const char* rB1 = (const char*)&lds[b][3][0];
        ushort_t* d0 = &lds[1 - b][0][0] + wave * 512;
        ushort_t* d1 = &lds[1 - b][1][0] + wave * 512;
        ushort_t* d2 = &lds[1 - b][2][0] + wave * 512;
        ushort_t* d3 = &lds[1 - b][3][0] + wave * 512;

        // ---- phase 0: Khalf0, m 0-3 ----
        asm volatile("s_waitcnt vmcnt(4)" ::: "memory");
        asm volatile("s_barrier" ::: "memory");
        #pragma unroll
        for (int i = 0; i < 4; ++i) av[i] = *(const short8*)(rA0 + abase + i * 1024);
        #pragma unroll
        for (int i = 0; i < 4; ++i) bv[i] = *(const short8*)(rB0 + bbase + i * 1024);
        if (pf) { GLOAD(pa + go, d0); GLOAD(pa + go + rstep, d0 + 4096); }
        __builtin_amdgcn_s_setprio(1);
        #pragma unroll
        for (int i = 0; i < 4; ++i)
            #pragma unroll
            for (int j = 0; j < 4; ++j) acc[i][j] = MFMA16(bv[j], av[i], acc[i][j]);
        __builtin_amdgcn_s_setprio(0);

        // ---- phase 1: Khalf0, m 4-7 (reuse bv) ----
        asm volatile("s_barrier" ::: "memory");
        #pragma unroll
        for (int i = 0; i < 4; ++i) av[i] = *(const short8*)(rA0 + abase + (4 + i) * 1024);
        if (pf) { GLOAD(pb + go, d1); GLOAD(pb + go + rstep, d1 + 4096); }
        __builtin_amdgcn_s_setprio(1);
        #pragma unroll
        for (int i = 0; i < 4; ++i)
            #pragma unroll
            for (int j = 0; j < 4; ++j) acc[4 + i][j] = MFMA16(bv[j], av[i], acc[4 + i][j]);
        __builtin_amdgcn_s_setprio(0);

        // ---- phase 2: Khalf1, m 0-3 ----
        if (pf) { asm volatile("s_waitcnt vmcnt(4)" ::: "memory"); }
        else    { asm volatile("s_waitcnt vmcnt(0)" ::: "memory"); }
        asm volatile("s_barrier" ::: "memory");
        #pragma unroll
        for (int i = 0; i < 4; ++i) av[i] = *(const short8*)(rA1 + abase + i * 1024);
        #pragma unroll
        for (int i = 0; i < 4; ++i) bv[i] = *(const short8*)(rB1 + bbase + i * 1024);
        if (pf) { GLOAD(pa + go + 32, d2); GLOAD(pa + go + 32 + rstep, d2 + 4096); }
        __builtin_amdgcn_s_setprio(1);
        #pragma unroll
        for (int i = 0; i < 4; ++i)
            #pragma unroll
            for (int j = 0; j < 4; ++j) acc[i][j] = MFMA16(bv[j], av[i], acc[i][j]);
        __builtin_amdgcn_s_setprio(0);

        // ---- phase 3: Khalf1, m 4-7 ----
        asm volatile("s_barrier" ::: "memory");
        #pragma unroll
        for (int i = 0; i < 4; ++i) av[i] = *(const short8*)(rA1 + abase + (4 + i) * 1024);
        if (pf) { GLOAD(pb + go + 32, d3); GLOAD(pb + go + 32 + rstep, d3 + 4096); }
        __builtin_amdgcn_s_setprio(1);
        #pragma unroll
        for (int i = 0; i < 4; ++i)
            #pragma unroll
            for (int j = 0; j < 4; ++j) acc[4 + i][j] = MFMA16(bv[j], av[i], acc[4 + i][j]);
        __builtin_amdgcn_s_setprio(0);
    }

    // ---- epilogue: swapped layout -> swizzled LDS bf16 tile -> coalesced stores ----
    __syncthreads();   // all K-loop LDS reads complete before overwrite
    char* L = (char*)&lds[0][0][0];   // [256 rows][512 B], chunk16 ^= (row&31)

    // bias per lane: 4 consecutive cols per n-frag
    float4 bias4[4];
    #pragma unroll
    for (int n = 0; n < 4; ++n)
        bias4[n] = *(const float4*)&bias[col0 + wn * 64 + n * 16 + kg * 4];

    #pragma unroll
    for (int m = 0; m < 8; ++m) {
        const int row_t = wm * 128 + m * 16 + fr;
        const long grow = (row0 + row_t) * (long)N;
        #pragma unroll
        for (int n = 0; n < 4; ++n) {
            const int colr = wn * 64 + n * 16 + kg * 4;     // col within tile
            float v0 = acc[m][n][0] + bias4[n].x;
            float v1 = acc[m][n][1] + bias4[n].y;
            float v2 = acc[m][n][2] + bias4[n].z;
            float v3 = acc[m][n][3] + bias4[n].w;
            if constexpr (EPI == 1) {
                v0 = fmaxf(v0, 0.f); v1 = fmaxf(v1, 0.f);
                v2 = fmaxf(v2, 0.f); v3 = fmaxf(v3, 0.f);
            }
            if constexpr (EPI == 2) {
                if constexpr (sizeof(ResT) == 4) {
                    float4 r4 = *(const float4*)&Res[grow + col0 + colr];
                    v0 += r4.x; v1 += r4.y; v2 += r4.z; v3 += r4.w;
                } else {
                    ushort4 r4 = *(const ushort4*)&Res[grow + col0 + colr];
                    v0 += b2f(r4.x); v1 += b2f(r4.y); v2 += b2f(r4.z); v3 += b2f(r4.w);
                }
            }
            ushort4 pk; pk.x = f2b(v0); pk.y = f2b(v1); pk.z = f2b(v2); pk.w = f2b(v3);
            const int cbyte = colr * 2;                      // 0..510
            const int chunk = cbyte >> 4;                    // 0..31
            const int addr  = row_t * 512 + ((chunk ^ (row_t & 31)) << 4) + (cbyte & 15);
            *(ushort4*)(L + addr) = pk;
        }
    }
    __syncthreads();

    // readback: 4 lanes per row -> 64B contiguous store segments
    #pragma unroll
    for (int p = 0; p < 2; ++p) {
        const int row_t = p * 128 + (tid >> 2);
        const long grow = (row0 + row_t) * (long)N + col0;
        #pragma unroll
        for (int k = 0; k < 8; ++k) {
            const int chunk = k * 4 + (tid & 3);
            short8 d = *(const short8*)(L + row_t * 512 + ((chunk ^ (row_t & 31)) << 4));
            *(short8*)&C[grow + chunk * 8] = d;
        }
    }
}

// ---------------- per-(window,head) attention: q,k,v [7,64]; one wave per block ----------------
__global__ __launch_bounds__(64)
void attn_kernel(const ushort_t* __restrict__ qkv, ushort_t* __restrict__ o)
{
    const int bid  = blockIdx.x;
    const int win  = bid >> 4;
    const int head = bid & 15;
    const int lane = threadIdx.x;
    __shared__ float qs[7][64], ks[7][64], vs[7][64];
    __shared__ float sc[7][8], pr[7][8];
    const long t0 = (long)win * 7;
    const ushort_t* base = qkv + t0 * 3072 + head * 64 + lane;
    #pragma unroll
    for (int i = 0; i < 7; ++i) {
        qs[i][lane] = b2f(base[(long)i * 3072]);
        ks[i][lane] = b2f(base[(long)i * 3072 + 1024]);
        vs[i][lane] = b2f(base[(long)i * 3072 + 2048]);
    }
    __syncthreads();
    if (lane < 49) {
        int i = lane / 7, j = lane % 7;
        float a = 0.f;
        #pragma unroll
        for (int d = 0; d < 64; ++d) a += qs[i][d] * ks[j][d];
        sc[i][j] = a * 0.125f;
    }
    __syncthreads();
    if (lane < 7) {
        float m = sc[lane][0];
        #pragma unroll
        for (int j = 1; j < 7; ++j) m = fmaxf(m, sc[lane][j]);
        float e[7], den = 0.f;
        #pragma unroll
        for (int j = 0; j < 7; ++j) { e[j] = __expf(sc[lane][j] - m); den += e[j]; }
        float inv = 1.f / den;
        #pragma unroll
        for (int j = 0; j < 7; ++j) pr[lane][j] = e[j] * inv;
    }
    __syncthreads();
    ushort_t* ob = o + t0 * 1024 + head * 64 + lane;
    #pragma unroll
    for (int i = 0; i < 7; ++i) {
        float a = 0.f;
        #pragma unroll
        for (int j = 0; j < 7; ++j) a += pr[i][j] * vs[j][lane];
        ob[(long)i * 1024] = f2b(a);
    }
}

// ---------------- row LayerNorm over H=1024; 256 threads, 4 elems/thread ----------------
template<typename OutT>
__global__ __launch_bounds__(256)
void ln_kernel(const ushort_t* in, OutT* out,
               const float* __restrict__ g, const float* __restrict__ b)
{
    const long row = blockIdx.x;
    const int tid = threadIdx.x;
    const ushort_t* p = in + row * H_;
    ushort4 raw = ((const ushort4*)p)[tid];
    float x0 = b2f(raw.x), x1 = b2f(raw.y), x2 = b2f(raw.z), x3 = b2f(raw.w);
    float s  = x0 + x1 + x2 + x3;
    float ss = x0*x0 + x1*x1 + x2*x2 + x3*x3;
    #pragma unroll
    for (int off = 32; off > 0; off >>= 1) {
        s  += __shfl_down(s,  off, 64);
        ss += __shfl_down(ss, off, 64);
    }
    __shared__ float rs[4], rss[4];
    const int wave = tid >> 6, lane = tid & 63;
    if (lane == 0) { rs[wave] = s; rss[wave] = ss; }
    __syncthreads();
    float S  = rs[0] + rs[1] + rs[2] + rs[3];
    float SS = rss[0] + rss[1] + rss[2] + rss[3];
    float mean = S * (1.f / 1024.f);
    float var  = SS * (1.f / 1024.f) - mean * mean;
    float inv  = rsqrtf(var + 1e-5f);
    float4 gv = ((const float4*)g)[tid];
    float4 bvv = ((const float4*)b)[tid];
    float y0 = (x0 - mean) * inv * gv.x + bvv.x;
    float y1 = (x1 - mean) * inv * gv.y + bvv.y;
    float y2 = (x2 - mean) * inv * gv.z + bvv.z;
    float y3 = (x3 - mean) * inv * gv.w + bvv.w;
    if constexpr (sizeof(OutT) == 2) {
        ushort4 ov; ov.x = f2b(y0); ov.y = f2b(y1); ov.z = f2b(y2); ov.w = f2b(y3);
        ((ushort4*)out)[row * 256 + tid] = ov;
    } else {
        float4 ov; ov.x = y0; ov.y = y1; ov.z = y2; ov.w = y3;
        ((float4*)out)[row * 256 + tid] = ov;
    }
}

// ---------------- launch ----------------
extern "C" void kernel_launch(void* const* d_in, const int* in_sizes, int n_in,
                              void* d_out, int out_size, void* d_ws, size_t ws_size,
                              hipStream_t stream)
{
    const float* x      = (const float*)d_in[0];
    const float* wqkv_f = (const float*)d_in[1];
    const float* bqkv   = (const float*)d_in[2];
    const float* wout_f = (const float*)d_in[3];
    const float* bout   = (const float*)d_in[4];
    const float* ln1g   = (const float*)d_in[5];
    const float* ln1b   = (const float*)d_in[6];
    const float* ln2g   = (const float*)d_in[7];
    const float* ln2b   = (const float*)d_in[8];
    const float* wff1_f = (const float*)d_in[9];
    const float* bff1   = (const float*)d_in[10];
    const float* wff2_f = (const float*)d_in[11];
    const float* bff2   = (const float*)d_in[12];
    float* out = (float*)d_out;

    const size_t WQKV_N = 3072l * 1024, WOUT_N = 1024l * 1024;
    const size_t WFF1_N = 4096l * 1024, WFF2_N = 1024l * 4096;
    const size_t welems = WQKV_N + WOUT_N + WFF1_N + WFF2_N;

    // chunk rows R: multiple of lcm(7,256)=1792; per-chunk arena = R*14336 B + weights
    int nc = 1;
    while (nc < 16 && (size_t)(MTOT / nc) * 14336 + welems * 2 > ws_size) nc <<= 1;
    const long R = MTOT / nc;

    char* ws = (char*)d_ws;
    ushort_t* qkv  = (ushort_t*)ws;                          // [R,3072]
    ushort_t* obuf = (ushort_t*)(ws + (size_t)R * 3072 * 2); // [R,1024]
    ushort_t* ff   = qkv;                                    // [R,4096] reuses qkv+obuf
    ushort_t* ybuf = (ushort_t*)(ws + (size_t)R * 4096 * 2); // [R,1024]
    ushort_t* s2   = (ushort_t*)(ws + (size_t)R * 5120 * 2); // [R,1024]
    ushort_t* xb   = (ushort_t*)(ws + (size_t)R * 6144 * 2); // [R,1024]
    ushort_t* wq   = (ushort_t*)(ws + (size_t)R * 7168 * 2);
    ushort_t* wo   = wq + WQKV_N;
    ushort_t* w1   = wo + WOUT_N;
    ushort_t* w2   = w1 + WFF1_N;

    f2b_kernel<<<WQKV_N / 1024, 256, 0, stream>>>(wqkv_f, wq);
    f2b_kernel<<<WOUT_N / 1024, 256, 0, stream>>>(wout_f, wo);
    f2b_kernel<<<WFF1_N / 1024, 256, 0, stream>>>(wff1_f, w1);
    f2b_kernel<<<WFF2_N / 1024, 256, 0, stream>>>(wff2_f, w2);

    for (int c = 0; c < nc; ++c) {
        const float* xc = x + (size_t)c * R * H_;
        float* oc = out + (size_t)c * R * H_;
        const int GY = R / 256;
        f2b_kernel<<<(R * H_) / 1024, 256, 0, stream>>>(xc, xb);
        // qkv = x @ Wqkv^T + b
        gemm_bt<0, float><<<12 * GY, 512, 0, stream>>>(xb, wq, bqkv, (const float*)nullptr, qkv, 3072, 1024, 12);
        // windowed attention
        attn_kernel<<<(R / 7) * 16, 64, 0, stream>>>(qkv, obuf);
        // s1 = x + o @ Wout^T + b   (residual in fp32 from original x)
        gemm_bt<2, float><<<4 * GY, 512, 0, stream>>>(obuf, wo, bout, xc, ybuf, 1024, 1024, 4);
        // y = LN1(s1), in place
        ln_kernel<ushort_t><<<R, 256, 0, stream>>>(ybuf, ybuf, ln1g, ln1b);
        // ff = relu(y @ W1^T + b1)
        gemm_bt<1, float><<<16 * GY, 512, 0, stream>>>(ybuf, w1, bff1, (const float*)nullptr, ff, 4096, 1024, 16);
        // s2 = y + ff @ W2^T + b2
        gemm_bt<2, ushort_t><<<4 * GY, 512, 0, stream>>>(ff, w2, bff2, ybuf, s2, 1024, 4096, 4);
        // out = LN2(s2), fp32
        ln_kernel<float><<<R, 256, 0, stream>>>(s2, oc, ln2g, ln2b);
    }
}